// Round 4
// baseline (670.613 us; speedup 1.0000x reference)
//
#include <hip/hip_runtime.h>
#include <hip/hip_bf16.h>
#include <math.h>

#define SS    16
#define NN    1024
#define RR    4
#define CINC  128
#define COUTC 128
#define RP1   5
#define EPSF  1e-7f

typedef __bf16 bf16x8 __attribute__((ext_vector_type(8)));
typedef __bf16 bf16x4 __attribute__((ext_vector_type(4)));
typedef float  f32x4  __attribute__((ext_vector_type(4)));

// Workspace layout:
//   Yt : bf16 [S*4][COUT][N]  (Y_c = X_s @ W_c, b-major)   16 MiB @ 0
//   wT : bf16 [5][COUT][CIN]  (W_c^T, ch4 = theta^T)      160 KiB @ 16 MiB
#define YT_BYTES ((size_t)SS * RR * COUTC * NN * 2)

// ---------------------------------------------------------------------------
// Stage 0: wT[c][b][a] = bf16(weight[a][b][c]), wT[4][b][a] = bf16(theta[a][b])
// ---------------------------------------------------------------------------
__global__ __launch_bounds__(256) void convert_kernel(
    const float* __restrict__ weight, const float* __restrict__ theta,
    __bf16* __restrict__ wT)
{
    const int idx = blockIdx.x * 256 + threadIdx.x;   // 0..16383
    const int a = idx >> 7, b = idx & 127;
    f32x4 wv = *(const f32x4*)(weight + ((size_t)a * COUTC + b) * RR);
    wT[(0 * COUTC + b) * CINC + a] = (__bf16)wv.x;
    wT[(1 * COUTC + b) * CINC + a] = (__bf16)wv.y;
    wT[(2 * COUTC + b) * CINC + a] = (__bf16)wv.z;
    wT[(3 * COUTC + b) * CINC + a] = (__bf16)wv.w;
    wT[(4 * COUTC + b) * CINC + a] = (__bf16)theta[(size_t)a * COUTC + b];
}

// ---------------------------------------------------------------------------
// Stage 1: Yt[(s*4+c)*128+b][j] = bf16( sum_a x[s][j][a] * wT[c][b][a] )
// No LDS, no barriers. bx = (jt*4+ch)*16+s -> XCD = s%8 (Yt_s produced into
// the same XCD L2 that main_kernel reads it from).
// ---------------------------------------------------------------------------
__global__ __launch_bounds__(256) void prep_kernel(
    const float* __restrict__ x, const __bf16* __restrict__ wT,
    __bf16* __restrict__ Yt)
{
    const int bx = blockIdx.x;
    const int s  = bx & 15;
    const int r  = bx >> 4;          // 0..63
    const int ch = r & 3;
    const int jt = r >> 2;           // 0..15  (64-token tile)

    const int t = threadIdx.x, lane = t & 63, w = t >> 6;
    const int m16 = lane & 15, quad = lane >> 4;

    const float*  xrow = x  + ((size_t)(s * NN) + jt * 64 + w * 16 + m16) * CINC;
    const __bf16* wch  = wT + (size_t)ch * COUTC * CINC;

    f32x4 acc[8];
#pragma unroll
    for (int i = 0; i < 8; ++i) acc[i] = (f32x4){0.f, 0.f, 0.f, 0.f};

#pragma unroll
    for (int k0 = 0; k0 < CINC; k0 += 32) {
        f32x4 xa = *(const f32x4*)(xrow + k0 + quad * 8);
        f32x4 xc = *(const f32x4*)(xrow + k0 + quad * 8 + 4);
        bf16x8 af;
        af[0] = (__bf16)xa.x; af[1] = (__bf16)xa.y; af[2] = (__bf16)xa.z; af[3] = (__bf16)xa.w;
        af[4] = (__bf16)xc.x; af[5] = (__bf16)xc.y; af[6] = (__bf16)xc.z; af[7] = (__bf16)xc.w;
#pragma unroll
        for (int bs = 0; bs < 8; ++bs) {
            const bf16x8 bf = *(const bf16x8*)(wch + (size_t)(bs * 16 + m16) * CINC + k0 + quad * 8);
            acc[bs] = __builtin_amdgcn_mfma_f32_16x16x32_bf16(af, bf, acc[bs], 0, 0, 0);
        }
    }

    const int j0 = jt * 64 + w * 16 + quad * 4;      // token row base (C/D rows)
#pragma unroll
    for (int bs = 0; bs < 8; ++bs) {
        const int b = bs * 16 + m16;
        bf16x4 v; v[0] = (__bf16)acc[bs][0]; v[1] = (__bf16)acc[bs][1];
                  v[2] = (__bf16)acc[bs][2]; v[3] = (__bf16)acc[bs][3];
        *(bf16x4*)(Yt + ((size_t)((s * 4 + ch) * COUTC + b)) * NN + j0) = v;
    }
}

// ---------------------------------------------------------------------------
// Main: out[s,i,b] = tanh( (x@theta)[s,i,b]
//                        + sum_c norm[s,i,c] * sum_j Ar[s,i,j,c]*Y_c[j,b] )
// NO LDS, NO BARRIERS. Each lane loads its own MFMA A-fragment straight from
// global: lane(m16,quad) reads A[s][i0+m16][kk*32+quad*8 .. +7][0..4] = 40
// contiguous dwords = 10 aligned dwordx4 (base is a multiple of 160 B).
// De-interleave + bf16 convert + fp32 row-sum in registers. The block's 4
// waves read the same A bytes (b-split w*32) -> L1/XCD-L2 absorbs the 4x.
// Row-sums: shfl_xor over quads; norm redistribution to C-layout rows via
// 16 shfl's. grid = 64 itile * 16 s = 1024 blocks; bx%8 = s%8 -> XCD-local Y.
// 12 free-running waves/CU x 10 KB in flight each >> 9 KB needed for full
// per-CU HBM share: latency hidden by TLP, no pipelining required.
// ---------------------------------------------------------------------------
__global__ __launch_bounds__(256, 3) void main_kernel(
    const float* __restrict__ A, const float* __restrict__ x,
    const __bf16* __restrict__ Yt, const __bf16* __restrict__ wT,
    float* __restrict__ out)
{
    const int bx = blockIdx.x;
    const int s  = bx & 15;
    const int i0 = (bx >> 4) * 16;

    const int t = threadIdx.x;
    const int lane = t & 63, w = t >> 6;
    const int m16 = lane & 15, quad = lane >> 4;

    // ---- theta term: accz[bs] = (x @ theta) fragment, straight MFMA ----
    f32x4 accz[2];
    accz[0] = (f32x4){0.f, 0.f, 0.f, 0.f};
    accz[1] = (f32x4){0.f, 0.f, 0.f, 0.f};
    {
        const float*  xrow = x  + ((size_t)(s * NN) + i0 + m16) * CINC;
        const __bf16* wth  = wT + (size_t)4 * COUTC * CINC;
#pragma unroll
        for (int k0 = 0; k0 < CINC; k0 += 32) {
            f32x4 xa = *(const f32x4*)(xrow + k0 + quad * 8);
            f32x4 xc = *(const f32x4*)(xrow + k0 + quad * 8 + 4);
            bf16x8 af;
            af[0] = (__bf16)xa.x; af[1] = (__bf16)xa.y; af[2] = (__bf16)xa.z; af[3] = (__bf16)xa.w;
            af[4] = (__bf16)xc.x; af[5] = (__bf16)xc.y; af[6] = (__bf16)xc.z; af[7] = (__bf16)xc.w;
#pragma unroll
            for (int bs = 0; bs < 2; ++bs) {
                const bf16x8 bf = *(const bf16x8*)(wth + (size_t)(w * 32 + bs * 16 + m16) * CINC + k0 + quad * 8);
                accz[bs] = __builtin_amdgcn_mfma_f32_16x16x32_bf16(af, bf, accz[bs], 0, 0, 0);
            }
        }
    }

    float rs[4] = {0.f, 0.f, 0.f, 0.f};
    f32x4 acc[4][2];
#pragma unroll
    for (int c = 0; c < 4; ++c)
#pragma unroll
        for (int bs = 0; bs < 2; ++bs) acc[c][bs] = (f32x4){0.f, 0.f, 0.f, 0.f};

    const __bf16* Ys = Yt + (size_t)s * 4 * COUTC * NN;
    // lane's A chunk: row i0+m16, j-window base quad*8, all 5 channels
    const f32x4* Ap = (const f32x4*)(A + (((size_t)(s * NN + i0 + m16) * NN) + quad * 8) * RP1);

    for (int kk = 0; kk < 32; ++kk) {
        // A: 10 aligned dwordx4 = 8 j's x 5 ch for this lane's row
        f32x4 ld[10];
#pragma unroll
        for (int u = 0; u < 10; ++u) ld[u] = Ap[u];

        // B-fragments from global (XCD-local L2-resident Y), issued after A:
        // waiting on A (older) leaves these in flight; MFMA then waits B only.
        bf16x8 bfr[4][2];
        const __bf16* yp = Ys + kk * 32 + quad * 8;
#pragma unroll
        for (int c = 0; c < 4; ++c)
#pragma unroll
            for (int bs = 0; bs < 2; ++bs)
                bfr[c][bs] = *(const bf16x8*)(yp + (size_t)(c * COUTC + w * 32 + bs * 16 + m16) * NN);

        // de-interleave channels, row-sum in fp32, convert to bf16 A-frags
#pragma unroll
        for (int c = 0; c < 4; ++c) {
            bf16x8 af;
            float sum = 0.f;
#pragma unroll
            for (int j = 0; j < 8; ++j) {
                const int d = j * RP1 + c;
                const float v = ld[d >> 2][d & 3];
                sum += v;
                af[j] = (__bf16)v;
            }
            rs[c] += sum;
            acc[c][0] = __builtin_amdgcn_mfma_f32_16x16x32_bf16(af, bfr[c][0], acc[c][0], 0, 0, 0);
            acc[c][1] = __builtin_amdgcn_mfma_f32_16x16x32_bf16(af, bfr[c][1], acc[c][1], 0, 0, 0);
        }

        Ap += 40;   // 32 j * 5 ch / 4
    }

    // row-sums: lane holds row i0+m16's partial (its quad's j-slices);
    // xor-reduce across quads -> every lane has the full sum for row m16
    float nrm[4];
#pragma unroll
    for (int c = 0; c < 4; ++c) {
        float v = rs[c];
        v += __shfl_xor(v, 16);
        v += __shfl_xor(v, 32);
        nrm[c] = 1.0f / (v + EPSF);
    }

    // redistribute norms to C-layout rows (row = quad*4 + r lives at lane quad*4+r)
    float nr[4][4];
#pragma unroll
    for (int c = 0; c < 4; ++c)
#pragma unroll
        for (int r = 0; r < 4; ++r)
            nr[c][r] = __shfl(nrm[c], quad * 4 + r);

    // epilogue: combine c's with norms, add theta term, tanh, store
#pragma unroll
    for (int bs = 0; bs < 2; ++bs) {
        const int b = w * 32 + bs * 16 + m16;
#pragma unroll
        for (int r = 0; r < 4; ++r) {
            float v = acc[0][bs][r] * nr[0][r]
                    + acc[1][bs][r] * nr[1][r]
                    + acc[2][bs][r] * nr[2][r]
                    + acc[3][bs][r] * nr[3][r]
                    + accz[bs][r];
            out[((size_t)s * NN + i0 + quad * 4 + r) * COUTC + b] = tanhf(v);
        }
    }
}

extern "C" void kernel_launch(void* const* d_in, const int* in_sizes, int n_in,
                              void* d_out, int out_size, void* d_ws, size_t ws_size,
                              hipStream_t stream)
{
    const float* A      = (const float*)d_in[0];
    const float* x      = (const float*)d_in[1];
    const float* weight = (const float*)d_in[2];
    const float* theta  = (const float*)d_in[3];
    float* out = (float*)d_out;

    __bf16* Yt = (__bf16*)d_ws;
    __bf16* wT = (__bf16*)((char*)d_ws + YT_BYTES);

    convert_kernel<<<dim3(64), dim3(256), 0, stream>>>(weight, theta, wT);
    prep_kernel<<<dim3(SS * RR * 16), dim3(256), 0, stream>>>(x, wT, Yt);
    main_kernel<<<dim3(SS * 64), dim3(256), 0, stream>>>(A, x, Yt, wT, out);
}